// Round 6
// baseline (564.748 us; speedup 1.0000x reference)
//
#include <hip/hip_runtime.h>
#include <stdint.h>

typedef __attribute__((ext_vector_type(8))) short short8;
typedef __attribute__((ext_vector_type(4))) float f32x4;
typedef __attribute__((ext_vector_type(4))) int i32x4;
typedef __attribute__((ext_vector_type(8))) unsigned short ushort8v;

#define NEGINF_F (-1000000.0f)
#define MFMA16 __builtin_amdgcn_mfma_f32_16x16x32_bf16

__device__ __forceinline__ unsigned short f2bf(float f) {
  union { float f; uint32_t u; } v; v.f = f;
  uint32_t r = (v.u + 0x7FFFu + ((v.u >> 16) & 1u)) >> 16;
  return (unsigned short)r;
}
__device__ __forceinline__ void gl_lds16(const void* g, void* l) {
  __builtin_amdgcn_global_load_lds(
      (const __attribute__((address_space(1))) void*)g,
      (__attribute__((address_space(3))) void*)l, 16, 0, 0);
}
#define BARRIER() asm volatile("s_barrier" ::: "memory")

// ---------------------------------------------------------------------------
// gemm256: C = A @ B^T, bf16 in, mfma 16x16x32 fp32 accum.
// 256x256 tile, BK=32, 512 thr = 8 waves (2M x 4N), 128x64 out per wave.
// K-loop: 4 LDS buffers (4 x 32KB), tile kt+2 staged DURING tile kt's two
// phases (2 loads/phase), boundary wait = s_waitcnt vmcnt(4) (tile kt+2's 4
// loads stay in flight -- never drains while work remains). Per phase:
// {ds_read frags | issue 2 global_load_lds | barrier | setprio(1) 16 MFMA
// setprio(0) | barrier}. BK=32 rows = 64B -> frag b128 reads are uniform
// 8 dwords/bank (bank-balanced, no swizzle needed; r1 measured).
// OUT32: full 256x256 fp32 tile staged through the 128KB LDS in two 128-row
// halves with per-row rotate swizzle -> i32x4 mask loads + f32x4 stores,
// fully coalesced (r4's scalar mask epilogue was the confounder).
// MASKED: int mask -> NEGINF applied in the vectorized epilogue.
// Requires M,N % 256 == 0, K % 32 == 0, K/32 >= 2.
// ---------------------------------------------------------------------------
template<bool MASKED, bool OUT32>
__global__ __launch_bounds__(512, 2)
void gemm256(const unsigned short* __restrict__ A,
             const unsigned short* __restrict__ B,
             void* __restrict__ Cv, const int* __restrict__ mask,
             int K, int lda, int ldb, int ldc,
             long sA, long sB, long sC, long sM, float scale)
{
  __shared__ __align__(16) unsigned short lds[4][16384];  // 128 KB

  const int t = threadIdx.x;
  const int b = blockIdx.z;
  const unsigned short* Ap = A + (long)b * sA;
  const unsigned short* Bp = B + (long)b * sB;
  const int* mp = MASKED ? (mask + (long)b * sM) : nullptr;
  const int tm = blockIdx.x * 256;
  const int tn = blockIdx.y * 256;

  const int lane = t & 63, wave = t >> 6;
  const int wm = (wave >> 2) * 128;      // waves 0-3: rows 0-127; 4-7: 128-255
  const int wn = (wave & 3) * 64;
  const int q = lane >> 4, mr = lane & 15;

  f32x4 acc[8][4];
#pragma unroll
  for (int m = 0; m < 8; m++)
#pragma unroll
    for (int n = 0; n < 4; n++) acc[m][n] = (f32x4){0.f, 0.f, 0.f, 0.f};

  const int srow = t >> 2;               // 0..127
  const int scol = (t & 3) * 8;          // 0,8,16,24 (shorts)

  auto stage_a = [&](int kt) {
    unsigned short* L = &lds[kt & 3][0];
    const unsigned short* ga = Ap + (long)(tm + srow) * lda + (kt << 5) + scol;
    gl_lds16(ga,                   L + (size_t)t * 8);          // rows 0-127
    gl_lds16(ga + (long)128 * lda, L + 4096 + (size_t)t * 8);   // rows 128-255
  };
  auto stage_b = [&](int kt) {
    unsigned short* L = &lds[kt & 3][0] + 8192;
    const unsigned short* gb = Bp + (long)(tn + srow) * ldb + (kt << 5) + scol;
    gl_lds16(gb,                   L + (size_t)t * 8);
    gl_lds16(gb + (long)128 * ldb, L + 4096 + (size_t)t * 8);
  };

  const int NT = K >> 5;
  stage_a(0); stage_b(0); stage_a(1); stage_b(1);   // 8 loads in flight
  asm volatile("s_waitcnt vmcnt(4)" ::: "memory");  // tile 0 landed (mine)
  BARRIER();                                        // landed (all waves)

  for (int kt = 0; kt < NT; ++kt) {
    const unsigned short* LA = &lds[kt & 3][0];
    const unsigned short* LB = LA + 8192;
    short8 af[8], b0, b1;
    // ---- phase 0: A frags + B n=0,1 ; stage A(kt+2) ----
#pragma unroll
    for (int m = 0; m < 8; m++)
      af[m] = *(const short8*)&LA[(size_t)(wm + m * 16 + mr) * 32 + q * 8];
    b0 = *(const short8*)&LB[(size_t)(wn + 0 * 16 + mr) * 32 + q * 8];
    b1 = *(const short8*)&LB[(size_t)(wn + 1 * 16 + mr) * 32 + q * 8];
    if (kt + 2 < NT) stage_a(kt + 2);
    BARRIER();
    __builtin_amdgcn_s_setprio(1);
#pragma unroll
    for (int m = 0; m < 8; m++) acc[m][0] = MFMA16(af[m], b0, acc[m][0], 0, 0, 0);
#pragma unroll
    for (int m = 0; m < 8; m++) acc[m][1] = MFMA16(af[m], b1, acc[m][1], 0, 0, 0);
    __builtin_amdgcn_s_setprio(0);
    BARRIER();
    // ---- phase 1: B n=2,3 ; stage B(kt+2) ----
    b0 = *(const short8*)&LB[(size_t)(wn + 2 * 16 + mr) * 32 + q * 8];
    b1 = *(const short8*)&LB[(size_t)(wn + 3 * 16 + mr) * 32 + q * 8];
    if (kt + 2 < NT) stage_b(kt + 2);
    BARRIER();
    __builtin_amdgcn_s_setprio(1);
#pragma unroll
    for (int m = 0; m < 8; m++) acc[m][2] = MFMA16(af[m], b0, acc[m][2], 0, 0, 0);
#pragma unroll
    for (int m = 0; m < 8; m++) acc[m][3] = MFMA16(af[m], b1, acc[m][3], 0, 0, 0);
    __builtin_amdgcn_s_setprio(0);
    // ---- tile boundary: counted wait (tile kt+1 ready; kt+2 may fly) ----
    if (kt + 1 < NT) {
      if (kt + 2 < NT) asm volatile("s_waitcnt vmcnt(4)" ::: "memory");
      else             asm volatile("s_waitcnt vmcnt(0)" ::: "memory");
      BARRIER();
    }
  }

  if (OUT32) {
    // two 128-row halves staged through LDS (128x256 fp32 = 128 KB),
    // per-row rotate swizzle (col + row*4)&255; vectorized mask + store.
    float* ep = (float*)&lds[0][0];
    float* co = (float*)Cv + (long)b * sC;
    const int myh = wave >> 2;
    const int tr = t >> 2;                  // 0..127 read row
    const int cb = (t & 3) * 64;            // read col base
#pragma unroll
    for (int h = 0; h < 2; h++) {
      __syncthreads();
      if (myh == h) {
#pragma unroll
        for (int m = 0; m < 8; m++)
#pragma unroll
          for (int n = 0; n < 4; n++)
#pragma unroll
            for (int r = 0; r < 4; r++) {
              const int lr = m * 16 + q * 4 + r;
              const int colr = (wn + n * 16 + mr + lr * 4) & 255;
              ep[lr * 256 + colr] = acc[m][n][r] * scale;
            }
      }
      __syncthreads();
      const int grow = tm + h * 128 + tr;
      const long rb = (long)grow * ldc + tn;
      const float* eprow = ep + tr * 256;
      const int rot = tr * 4;
#pragma unroll
      for (int j = 0; j < 16; j++) {
        const int LC = cb + j * 4;
        f32x4 x = *(const f32x4*)&eprow[(LC + rot) & 255];
        if (MASKED) {
          const i32x4 mv = *(const i32x4*)&mp[rb + LC];
#pragma unroll
          for (int e = 0; e < 4; e++)
            if (!mv[e]) x[e] = NEGINF_F;
        }
        *(f32x4*)&co[rb + LC] = x;
      }
    }
  } else {
    unsigned short* co = (unsigned short*)Cv + (long)b * sC;
#pragma unroll
    for (int m = 0; m < 8; m++)
#pragma unroll
      for (int n = 0; n < 4; n++) {
        const int row0 = tm + wm + m * 16 + q * 4;
        const int col  = tn + wn + n * 16 + mr;
#pragma unroll
        for (int r = 0; r < 4; r++)
          co[(long)(row0 + r) * ldc + col] = f2bf(acc[m][n][r] * scale);
      }
  }
}

// ---------------------------------------------------------------------------
// 128x128 gemm_nt (kept for the !use_pb fallback path only).
// ---------------------------------------------------------------------------
template<bool A32, bool OUT32>
__global__ __launch_bounds__(256, A32 ? 2 : 4)
void gemm_nt(const void* __restrict__ Av, const unsigned short* __restrict__ B,
             void* __restrict__ Cv,
             int K, int lda, int ldb, int ldc,
             long sA, long sB, long sC, float scale)
{
  constexpr int ABYTES = A32 ? 128 * 32 * 4 : 128 * 32 * 2;
  constexpr int BBYTES = 128 * 32 * 2;
  constexpr int BUFB = ABYTES + BBYTES;
  __shared__ __align__(16) unsigned char smem[2 * BUFB];

  const int t = threadIdx.x;
  const int b = blockIdx.z;
  const float* Af = (const float*)Av + (long)b * sA;
  const unsigned short* Ah = (const unsigned short*)Av + (long)b * sA;
  const unsigned short* Bp = B + (long)b * sB;
  const int tm = blockIdx.x * 128;
  const int tn = blockIdx.y * 128;

  const int lane = t & 63, wave = t >> 6;
  const int wm = (wave & 1) * 64, wn = (wave >> 1) * 64;
  const int q = lane >> 4, mr = lane & 15;

  f32x4 acc[4][4];
#pragma unroll
  for (int i = 0; i < 4; i++)
#pragma unroll
    for (int j = 0; j < 4; j++) acc[i][j] = (f32x4){0.f, 0.f, 0.f, 0.f};

  const int r0a = t >> 2;
  const int cswz = ((t & 3) ^ ((t >> 2) & 3)) * 8;
  const int sw8 = (q ^ (mr & 3)) * 8;

  auto stage = [&](int buf, int k0) {
    unsigned char* base = smem + buf * BUFB;
    if (A32) {
      float* Asf = (float*)base;
#pragma unroll
      for (int rd = 0; rd < 4; rd++) {
        const int f = rd * 1024 + t * 4;
        const int row = f >> 5, col = f & 31;
        gl_lds16(Af + (long)(tm + row) * lda + k0 + col, Asf + f);
      }
    } else {
      unsigned short* Ash = (unsigned short*)base;
      const unsigned short* ga = Ah + (long)(tm + r0a) * lda + k0 + cswz;
      gl_lds16(ga, &Ash[(size_t)t * 8]);
      gl_lds16(ga + (long)64 * lda, &Ash[(size_t)(t + 256) * 8]);
    }
    unsigned short* Bsb = (unsigned short*)(base + ABYTES);
    const unsigned short* gb = Bp + (long)(tn + r0a) * ldb + k0 + cswz;
    gl_lds16(gb, &Bsb[(size_t)t * 8]);
    gl_lds16(gb + (long)64 * ldb, &Bsb[(size_t)(t + 256) * 8]);
  };

  const int nt = K >> 5;
  stage(0, 0);
  __syncthreads();

  for (int ti = 0; ti < nt; ++ti) {
    if (ti + 1 < nt) stage((ti + 1) & 1, (ti + 1) << 5);

    const unsigned char* base = smem + (ti & 1) * BUFB;
    const unsigned short* Bs = (const unsigned short*)(base + ABYTES);
    short8 af[4], bfr[4];
#pragma unroll
    for (int i = 0; i < 4; i++) {
      if (A32) {
        const float* Asf = (const float*)base;
        const int fb = (wm + i * 16 + mr) * 32 + q * 8;
        const f32x4 x0 = *(const f32x4*)&Asf[fb];
        const f32x4 x1 = *(const f32x4*)&Asf[fb + 4];
        short8 v;
        v[0] = (short)f2bf(x0[0]); v[1] = (short)f2bf(x0[1]);
        v[2] = (short)f2bf(x0[2]); v[3] = (short)f2bf(x0[3]);
        v[4] = (short)f2bf(x1[0]); v[5] = (short)f2bf(x1[1]);
        v[6] = (short)f2bf(x1[2]); v[7] = (short)f2bf(x1[3]);
        af[i] = v;
      } else {
        const unsigned short* Ash = (const unsigned short*)base;
        af[i] = *(const short8*)&Ash[(size_t)(wm + i * 16 + mr) * 32 + sw8];
      }
      bfr[i] = *(const short8*)&Bs[(size_t)(wn + i * 16 + mr) * 32 + sw8];
    }
#pragma unroll
    for (int i = 0; i < 4; i++)
#pragma unroll
      for (int j = 0; j < 4; j++)
        acc[i][j] = MFMA16(af[i], bfr[j], acc[i][j], 0, 0, 0);

    if (ti + 1 < nt) __syncthreads();
  }

  if (OUT32) {
    float* ep = (float*)smem;
    float* co = (float*)Cv + (long)b * sC;
    const int band = wm >> 2;
    const int tr = t >> 3;
    const int tcb = (t & 7) * 16;
    const int growb = tm + (tr >> 4) * 64 + (tr & 15);
#pragma unroll
    for (int i = 0; i < 4; i++) {
      __syncthreads();
#pragma unroll
      for (int j = 0; j < 4; j++) {
        const int colb = wn + j * 16 + mr;
#pragma unroll
        for (int r = 0; r < 4; r++) {
          const int lr = band + q * 4 + r;
          ep[lr * 128 + ((colb + lr * 4) & 127)] = acc[i][j][r];
        }
      }
      __syncthreads();
      const int gr = growb + i * 16;
      const long rbase = (long)gr * ldc;
      const float* eprow = ep + tr * 128;
      const int rot = tr * 4;
#pragma unroll
      for (int k = 0; k < 4; k++) {
        const int lc = tcb + k * 4;
        f32x4 x = *(const f32x4*)&eprow[(lc + rot) & 127];
        x *= scale;
        *(f32x4*)&co[rbase + tn + lc] = x;
      }
    }
  } else {
#pragma unroll
    for (int i = 0; i < 4; i++) {
#pragma unroll
      for (int j = 0; j < 4; j++) {
        const int row0 = tm + wm + i * 16 + q * 4;
        const int col  = tn + wn + j * 16 + mr;
        const f32x4 v = acc[i][j];
#pragma unroll
        for (int r = 0; r < 4; r++) {
          float x = v[r] * scale;
          ((unsigned short*)Cv + (long)b * sC)[(long)(row0 + r) * ldc + col] = f2bf(x);
        }
      }
    }
  }
}

// one block per row of 2048 fp32: max -> sumexp -> normalize, in place.
// Mask was applied upstream (scores epilogue): masked = NEGINF -> exp = 0.
// Optionally emits the normalized row as bf16 to Pb (for the z GEMM).
__global__ __launch_bounds__(256) void softmax_rows_f32(
    float* __restrict__ P, unsigned short* __restrict__ Pb)
{
  const size_t row = blockIdx.x;
  float* p = P + row * 2048;
  const int t = threadIdx.x, lane = t & 63, wv = t >> 6;
  f32x4 a = *(const f32x4*)(p + t * 8);
  f32x4 c = *(const f32x4*)(p + t * 8 + 4);
  float x[8] = {a[0], a[1], a[2], a[3], c[0], c[1], c[2], c[3]};
  float mx = x[0];
#pragma unroll
  for (int j = 1; j < 8; j++) mx = fmaxf(mx, x[j]);
#pragma unroll
  for (int o = 32; o > 0; o >>= 1) mx = fmaxf(mx, __shfl_xor(mx, o));
  __shared__ float rm[4], rs[4];
  if (lane == 0) rm[wv] = mx;
  __syncthreads();
  mx = fmaxf(fmaxf(rm[0], rm[1]), fmaxf(rm[2], rm[3]));
  float e[8], s = 0.f;
#pragma unroll
  for (int j = 0; j < 8; j++) { e[j] = __expf(x[j] - mx); s += e[j]; }
#pragma unroll
  for (int o = 32; o > 0; o >>= 1) s += __shfl_xor(s, o);
  if (lane == 0) rs[wv] = s;
  __syncthreads();
  s = rs[0] + rs[1] + rs[2] + rs[3];
  // fully-masked row: mx stays NEGINF -> reference (softmax * mask) = 0
  const float linv = (mx < -1.0e5f) ? 0.f : 1.f / s;
  f32x4 o0 = {e[0] * linv, e[1] * linv, e[2] * linv, e[3] * linv};
  f32x4 o1 = {e[4] * linv, e[5] * linv, e[6] * linv, e[7] * linv};
  *(f32x4*)(p + t * 8) = o0;
  *(f32x4*)(p + t * 8 + 4) = o1;
  if (Pb) {
    ushort8v ob;
    ob[0] = f2bf(o0[0]); ob[1] = f2bf(o0[1]); ob[2] = f2bf(o0[2]); ob[3] = f2bf(o0[3]);
    ob[4] = f2bf(o1[0]); ob[5] = f2bf(o1[1]); ob[6] = f2bf(o1[2]); ob[7] = f2bf(o1[3]);
    *(ushort8v*)(Pb + row * 2048 + t * 8) = ob;
  }
}

// triple fp32 -> bf16 bulk convert (3 x 8388608 elems, blockIdx.y selects)
__global__ __launch_bounds__(256) void cvt3(
    const float* __restrict__ s0, unsigned short* __restrict__ d0,
    const float* __restrict__ s1, unsigned short* __restrict__ d1,
    const float* __restrict__ s2, unsigned short* __restrict__ d2)
{
  const float* s = blockIdx.y == 0 ? s0 : (blockIdx.y == 1 ? s1 : s2);
  unsigned short* d = blockIdx.y == 0 ? d0 : (blockIdx.y == 1 ? d1 : d2);
  const size_t i = ((size_t)blockIdx.x * 256 + threadIdx.x) * 8;
  const float4 a = *(const float4*)(s + i);
  const float4 b = *(const float4*)(s + i + 4);
  ushort8v o;
  o[0] = f2bf(a.x); o[1] = f2bf(a.y); o[2] = f2bf(a.z); o[3] = f2bf(a.w);
  o[4] = f2bf(b.x); o[5] = f2bf(b.y); o[6] = f2bf(b.z); o[7] = f2bf(b.w);
  *(ushort8v*)(d + i) = o;
}

// per-batch transpose+convert (fallback path only)
__global__ __launch_bounds__(256) void cvt_t_v(
    const float* __restrict__ src, unsigned short* __restrict__ dst)
{
  const int b = blockIdx.z;
  __shared__ float tile[32][33];
  const int s0 = blockIdx.x * 32, i0 = blockIdx.y * 32;
  const int tx = threadIdx.x & 31, ty = threadIdx.x >> 5;
#pragma unroll
  for (int r = 0; r < 4; r++) {
    const int srow = ty + r * 8;
    tile[srow][tx] = src[((size_t)b * 2048 + s0 + srow) * 512 + i0 + tx];
  }
  __syncthreads();
#pragma unroll
  for (int r = 0; r < 4; r++) {
    const int irow = ty + r * 8;
    dst[((size_t)b * 512 + i0 + irow) * 2048 + s0 + tx] = f2bf(tile[tx][irow]);
  }
}

// 512x512 transpose + fp32->bf16 (x3 weights)
__global__ __launch_bounds__(256) void transpose_w(
    const float* __restrict__ W0, const float* __restrict__ W1,
    const float* __restrict__ W2,
    unsigned short* __restrict__ T0, unsigned short* __restrict__ T1,
    unsigned short* __restrict__ T2)
{
  const float* W = blockIdx.z == 0 ? W0 : (blockIdx.z == 1 ? W1 : W2);
  unsigned short* T = blockIdx.z == 0 ? T0 : (blockIdx.z == 1 ? T1 : T2);
  __shared__ float tile[32][33];
  const int bx = blockIdx.x * 32, by = blockIdx.y * 32;
  const int tx = threadIdx.x & 31, ty = threadIdx.x >> 5;
#pragma unroll
  for (int i = 0; i < 4; i++) {
    const int r = ty + i * 8;
    tile[r][tx] = W[(size_t)(by + r) * 512 + bx + tx];
  }
  __syncthreads();
#pragma unroll
  for (int i = 0; i < 4; i++) {
    const int r = ty + i * 8;
    T[(size_t)(bx + r) * 512 + by + tx] = f2bf(tile[tx][r]);
  }
}

extern "C" void kernel_launch(void* const* d_in, const int* in_sizes, int n_in,
                              void* d_out, int out_size, void* d_ws, size_t ws_size,
                              hipStream_t stream) {
  const float* Xq = (const float*)d_in[0];
  const float* Xk = (const float*)d_in[1];
  const float* Xv = (const float*)d_in[2];
  const int*   mk = (const int*)d_in[3];
  const float* Wq = (const float*)d_in[4];
  const float* Wk = (const float*)d_in[5];
  const float* Wv = (const float*)d_in[6];

  float* z = (float*)d_out;                          // [8,2048,512] fp32
  float* P = z + (size_t)8 * 2048 * 512;             // [8,2048,2048] fp32

  unsigned short* w    = (unsigned short*)d_ws;
  unsigned short* Wtq  = w;                          // [2][262144]: Wtq, Wtk
  unsigned short* Wtv  = w + 524288;
  unsigned short* buf1 = w + 786432;                 // Qs, later Vw^T
  unsigned short* buf2 = buf1 + 8388608;             // Ks
  unsigned short* Pb   = buf2 + 8388608;             // 33554432 shorts
  const bool use_pb = ws_size >= (size_t)102236160;

  // bf16 scratch overlays in d_out regions written later:
  unsigned short* Xqkb = (unsigned short*)P;         // [2][8388608]
  unsigned short* Xvb  = (unsigned short*)z;

  const float inv_scale = 0.21022410381342863f;      // 512^-0.25

  transpose_w<<<dim3(16, 16, 3), 256, 0, stream>>>(Wq, Wk, Wv, Wtq, Wtq + 262144, Wtv);

  // Xq -> Xqkb[0], Xk -> Xqkb[1], Xv -> Xvb (bf16)
  cvt3<<<dim3(4096, 3), 256, 0, stream>>>(Xq, Xqkb, Xk, Xqkb + 8388608, Xv, Xvb);

  // Q and K projections in one launch (z selects input/weight/output)
  gemm256<false, false><<<dim3(64, 2, 2), 512, 0, stream>>>(
      Xqkb, Wtq, buf1, nullptr, 512, 512, 512, 512,
      8388608, 262144, 8388608, 0, inv_scale);

  // Scores: Qs_b @ Ks_b^T, vectorized mask epilogue -> P (fp32)
  gemm256<true, true><<<dim3(8, 8, 8), 512, 0, stream>>>(
      buf1, buf2, P, mk, 512, 512, 512, 2048,
      1048576, 1048576, 4194304, 4194304, 1.0f);

  softmax_rows_f32<<<dim3(16384), 256, 0, stream>>>(P, use_pb ? Pb : nullptr);

  if (use_pb) {
    // Vw^T[b][e][s] = sum_i Wtv[e][i] * Xvb[b][s][i]  -> buf1 (bf16)
    gemm256<false, false><<<dim3(2, 8, 8), 512, 0, stream>>>(
        Wtv, Xvb, buf1, nullptr, 512, 512, 512, 2048,
        0, 1048576, 1048576, 0, 1.0f);
    // z[b][q][e] = sum_s Pb[b][q][s] * Vw^T[b][e][s]  (fp32)
    gemm256<false, true><<<dim3(8, 2, 8), 512, 0, stream>>>(
        Pb, buf1, z, nullptr, 2048, 2048, 2048, 512,
        4194304, 1048576, 1048576, 0, 1.0f);
  } else {
    // fallback: A32 PV (reads fp32 attn_p) + z GEMM on the 128x128 kernel
    cvt_t_v<<<dim3(64, 16, 8), 256, 0, stream>>>(Xv, buf1);
    gemm_nt<true, false><<<dim3(16, 4, 8), 256, 0, stream>>>(
        P, buf1, buf2, 2048, 2048, 2048, 512,
        4194304, 1048576, 1048576, 1.0f);
    gemm_nt<false, true><<<dim3(128, 4, 1), 256, 0, stream>>>(
        buf2, Wtv, z, 512, 512, 512, 512, 0, 0, 0, 1.0f);
  }
}

// Round 8
// 525.577 us; speedup vs baseline: 1.0745x; 1.0745x over previous
//
#include <hip/hip_runtime.h>
#include <stdint.h>

typedef __attribute__((ext_vector_type(8))) short short8;
typedef __attribute__((ext_vector_type(4))) float f32x4;
typedef __attribute__((ext_vector_type(4))) int i32x4;
typedef __attribute__((ext_vector_type(8))) unsigned short ushort8v;

#define NEGINF_F (-1000000.0f)
#define MFMA16 __builtin_amdgcn_mfma_f32_16x16x32_bf16

__device__ __forceinline__ unsigned short f2bf(float f) {
  union { float f; uint32_t u; } v; v.f = f;
  uint32_t r = (v.u + 0x7FFFu + ((v.u >> 16) & 1u)) >> 16;
  return (unsigned short)r;
}
__device__ __forceinline__ void gl_lds16(const void* g, void* l) {
  __builtin_amdgcn_global_load_lds(
      (const __attribute__((address_space(1))) void*)g,
      (__attribute__((address_space(3))) void*)l, 16, 0, 0);
}

// ---------------------------------------------------------------------------
// 128x128 GEMM body: C = A @ B^T, bf16 in, mfma 16x16x32 fp32 accum. BK=32,
// 256 thr = 4 waves (2x2), 4x4 frags/wave.
// K-loop: r3-VERIFIED 2-buffer __syncthreads pipeline (stage ti+1 before
// compute of ti; one compiler-managed barrier per iter). The r7 3-buffer
// raw-barrier counted-vmcnt variant FAILED correctness (suspected: compiler
// sinks register-only MFMA past asm-"memory" barriers, rule #18 family) and
// is reverted.
// OUT32: fp32 C via LDS-staged vectorized epilogue; MASKED: i32x4 mask loads
// -> NEGINF (scalar mask reads measured 2.7 TB/s cap in r4).
// ---------------------------------------------------------------------------
template<bool OUT32, bool MASKED>
__device__ __forceinline__ void gemm_body(
    const unsigned short* __restrict__ Ap, const unsigned short* __restrict__ Bp,
    void* __restrict__ Cp, const int* __restrict__ mp,
    int K, int lda, int ldb, int ldc, int tm, int tn, float scale,
    unsigned short* lds)
{
  const int t = threadIdx.x;
  const int lane = t & 63, wave = t >> 6;
  const int wm = (wave & 1) * 64, wn = (wave >> 1) * 64;
  const int q = lane >> 4, mr = lane & 15;

  f32x4 acc[4][4];
#pragma unroll
  for (int i = 0; i < 4; i++)
#pragma unroll
    for (int j = 0; j < 4; j++) acc[i][j] = (f32x4){0.f, 0.f, 0.f, 0.f};

  const int r0a = t >> 2;                              // staging row
  const int cswz = ((t & 3) ^ ((t >> 2) & 3)) * 8;     // source pre-swizzle
  const int sw8 = (q ^ (mr & 3)) * 8;                  // frag-read swizzle

  auto stage = [&](int bi, int kt) {
    unsigned short* L = lds + bi * 8192;               // A [0,4096) B [4096,8192)
    const int k0 = kt << 5;
    const unsigned short* ga = Ap + (long)(tm + r0a) * lda + k0 + cswz;
    gl_lds16(ga, L + (size_t)t * 8);
    gl_lds16(ga + (long)64 * lda, L + (size_t)(t + 256) * 8);
    unsigned short* Lb = L + 4096;
    const unsigned short* gb = Bp + (long)(tn + r0a) * ldb + k0 + cswz;
    gl_lds16(gb, Lb + (size_t)t * 8);
    gl_lds16(gb + (long)64 * ldb, Lb + (size_t)(t + 256) * 8);
  };

  const int nt = K >> 5;
  stage(0, 0);
  __syncthreads();

  for (int ti = 0; ti < nt; ++ti) {
    if (ti + 1 < nt) stage((ti + 1) & 1, ti + 1);      // prefetch next

    const unsigned short* LA = lds + (ti & 1) * 8192;
    const unsigned short* LB = LA + 4096;
    short8 af[4], bfr[4];
#pragma unroll
    for (int i = 0; i < 4; i++) {
      af[i]  = *(const short8*)&LA[(size_t)(wm + i * 16 + mr) * 32 + sw8];
      bfr[i] = *(const short8*)&LB[(size_t)(wn + i * 16 + mr) * 32 + sw8];
    }
#pragma unroll
    for (int i = 0; i < 4; i++)
#pragma unroll
      for (int j = 0; j < 4; j++)
        acc[i][j] = MFMA16(af[i], bfr[j], acc[i][j], 0, 0, 0);

    if (ti + 1 < nt) __syncthreads();
  }

  // C/D layout (m89-verified): col = lane&15, row = (lane>>4)*4 + reg
  if (OUT32) {
    float* ep = (float*)lds;
    float* co = (float*)Cp;
    const int band = wm >> 2;                 // 0 or 16
    const int tr = t >> 3;                    // 0..31 read row
    const int tcb = (t & 7) * 16;
    const int growb = tm + (tr >> 4) * 64 + (tr & 15);
#pragma unroll
    for (int i = 0; i < 4; i++) {
      __syncthreads();
#pragma unroll
      for (int j = 0; j < 4; j++) {
        const int colb = wn + j * 16 + mr;
#pragma unroll
        for (int r = 0; r < 4; r++) {
          const int lr = band + q * 4 + r;
          ep[lr * 128 + ((colb + lr * 4) & 127)] = acc[i][j][r];
        }
      }
      __syncthreads();
      const int gr = growb + i * 16;
      const long rbase = (long)gr * ldc;
      const float* eprow = ep + tr * 128;
      const int rot = tr * 4;
#pragma unroll
      for (int k = 0; k < 4; k++) {
        const int lc = tcb + k * 4;
        f32x4 x = *(const f32x4*)&eprow[(lc + rot) & 127];
        x *= scale;
        if (MASKED) {
          const i32x4 mv = *(const i32x4*)&mp[rbase + tn + lc];
#pragma unroll
          for (int e = 0; e < 4; e++)
            if (!mv[e]) x[e] = NEGINF_F;
        }
        *(f32x4*)&co[rbase + tn + lc] = x;
      }
    }
  } else {
    unsigned short* co = (unsigned short*)Cp;
#pragma unroll
    for (int i = 0; i < 4; i++)
#pragma unroll
      for (int j = 0; j < 4; j++) {
        const int row0 = tm + wm + i * 16 + q * 4;
        const int col  = tn + wn + j * 16 + mr;
#pragma unroll
        for (int r = 0; r < 4; r++)
          co[(long)(row0 + r) * ldc + col] = f2bf(acc[i][j][r] * scale);
      }
  }
}

// proj3: roles by (blockIdx.z + zoff):
//  z=0/1: Q/K projection  A=Xqkb[z] [16384x512], B=Wt[z], C=QK[z] (bf16, scaled)
//  z=2:   Vw^T per batch  A=Wtv [512x512], B=Xvb_b [2048x512], C=Vwt_b [512x2048]
__global__ __launch_bounds__(256, 4) void proj3(
    const unsigned short* __restrict__ Xqkb, const unsigned short* __restrict__ Wtqk,
    unsigned short* __restrict__ QK,
    const unsigned short* __restrict__ Wtv, const unsigned short* __restrict__ Xvb,
    unsigned short* __restrict__ Vwt, float sc, int zoff)
{
  __shared__ __align__(16) unsigned short lds[16384];
  const int zz = blockIdx.z + zoff;
  if (zz < 2) {
    gemm_body<false, false>(Xqkb + (size_t)zz * 8388608, Wtqk + zz * 262144,
        QK + (size_t)zz * 8388608, nullptr, 512, 512, 512, 512,
        blockIdx.x * 128, blockIdx.y * 128, sc, lds);
  } else {
    const int bb = blockIdx.x >> 2;
    gemm_body<false, false>(Wtv, Xvb + (size_t)bb * 1048576,
        Vwt + (size_t)bb * 1048576, nullptr, 512, 512, 512, 2048,
        (blockIdx.x & 3) * 128, blockIdx.y * 128, 1.0f, lds);
  }
}

// scores: per batch Qs_b @ Ks_b^T, vectorized mask epilogue -> P fp32
__global__ __launch_bounds__(256, 4) void gemm_sc(
    const unsigned short* __restrict__ Qs, const unsigned short* __restrict__ Ks,
    float* __restrict__ P, const int* __restrict__ mk)
{
  __shared__ __align__(16) unsigned short lds[16384];
  const int b = blockIdx.z;
  gemm_body<true, true>(Qs + (size_t)b * 1048576, Ks + (size_t)b * 1048576,
      P + (size_t)b * 4194304, mk + (size_t)b * 4194304,
      512, 512, 512, 2048, blockIdx.x * 128, blockIdx.y * 128, 1.0f, lds);
}

// z: per batch Pb_b [2048x2048] @ Vwt_b^T [512x2048] -> z fp32 [2048x512]
__global__ __launch_bounds__(256, 4) void gemm_z(
    const unsigned short* __restrict__ Pb, const unsigned short* __restrict__ Vwt,
    float* __restrict__ z)
{
  __shared__ __align__(16) unsigned short lds[16384];
  const int b = blockIdx.z;
  gemm_body<true, false>(Pb + (size_t)b * 4194304, Vwt + (size_t)b * 1048576,
      z + (size_t)b * 1048576, nullptr,
      2048, 2048, 2048, 512, blockIdx.x * 128, blockIdx.y * 128, 1.0f, lds);
}

// ---------------------------------------------------------------------------
// 128x128 gemm_nt (r5-verified): fallback path only (A32 PV + z GEMM).
// ---------------------------------------------------------------------------
template<bool A32, bool OUT32>
__global__ __launch_bounds__(256, A32 ? 2 : 4)
void gemm_nt(const void* __restrict__ Av, const unsigned short* __restrict__ B,
             void* __restrict__ Cv,
             int K, int lda, int ldb, int ldc,
             long sA, long sB, long sC, float scale)
{
  constexpr int ABYTES = A32 ? 128 * 32 * 4 : 128 * 32 * 2;
  constexpr int BBYTES = 128 * 32 * 2;
  constexpr int BUFB = ABYTES + BBYTES;
  __shared__ __align__(16) unsigned char smem[2 * BUFB];

  const int t = threadIdx.x;
  const int b = blockIdx.z;
  const float* Af = (const float*)Av + (long)b * sA;
  const unsigned short* Ah = (const unsigned short*)Av + (long)b * sA;
  const unsigned short* Bp = B + (long)b * sB;
  const int tm = blockIdx.x * 128;
  const int tn = blockIdx.y * 128;

  const int lane = t & 63, wave = t >> 6;
  const int wm = (wave & 1) * 64, wn = (wave >> 1) * 64;
  const int q = lane >> 4, mr = lane & 15;

  f32x4 acc[4][4];
#pragma unroll
  for (int i = 0; i < 4; i++)
#pragma unroll
    for (int j = 0; j < 4; j++) acc[i][j] = (f32x4){0.f, 0.f, 0.f, 0.f};

  const int r0a = t >> 2;
  const int cswz = ((t & 3) ^ ((t >> 2) & 3)) * 8;
  const int sw8 = (q ^ (mr & 3)) * 8;

  auto stage = [&](int buf, int k0) {
    unsigned char* base = smem + buf * BUFB;
    if (A32) {
      float* Asf = (float*)base;
#pragma unroll
      for (int rd = 0; rd < 4; rd++) {
        const int f = rd * 1024 + t * 4;
        const int row = f >> 5, col = f & 31;
        gl_lds16(Af + (long)(tm + row) * lda + k0 + col, Asf + f);
      }
    } else {
      unsigned short* Ash = (unsigned short*)base;
      const unsigned short* ga = Ah + (long)(tm + r0a) * lda + k0 + cswz;
      gl_lds16(ga, &Ash[(size_t)t * 8]);
      gl_lds16(ga + (long)64 * lda, &Ash[(size_t)(t + 256) * 8]);
    }
    unsigned short* Bsb = (unsigned short*)(base + ABYTES);
    const unsigned short* gb = Bp + (long)(tn + r0a) * ldb + k0 + cswz;
    gl_lds16(gb, &Bsb[(size_t)t * 8]);
    gl_lds16(gb + (long)64 * ldb, &Bsb[(size_t)(t + 256) * 8]);
  };

  const int nt = K >> 5;
  stage(0, 0);
  __syncthreads();

  for (int ti = 0; ti < nt; ++ti) {
    if (ti + 1 < nt) stage((ti + 1) & 1, (ti + 1) << 5);

    const unsigned char* base = smem + (ti & 1) * BUFB;
    const unsigned short* Bs = (const unsigned short*)(base + ABYTES);
    short8 af[4], bfr[4];
#pragma unroll
    for (int i = 0; i < 4; i++) {
      if (A32) {
        const float* Asf = (const float*)base;
        const int fb = (wm + i * 16 + mr) * 32 + q * 8;
        const f32x4 x0 = *(const f32x4*)&Asf[fb];
        const f32x4 x1 = *(const f32x4*)&Asf[fb + 4];
        short8 v;
        v[0] = (short)f2bf(x0[0]); v[1] = (short)f2bf(x0[1]);
        v[2] = (short)f2bf(x0[2]); v[3] = (short)f2bf(x0[3]);
        v[4] = (short)f2bf(x1[0]); v[5] = (short)f2bf(x1[1]);
        v[6] = (short)f2bf(x1[2]); v[7] = (short)f2bf(x1[3]);
        af[i] = v;
      } else {
        const unsigned short* Ash = (const unsigned short*)base;
        af[i] = *(const short8*)&Ash[(size_t)(wm + i * 16 + mr) * 32 + sw8];
      }
      bfr[i] = *(const short8*)&Bs[(size_t)(wn + i * 16 + mr) * 32 + sw8];
    }
#pragma unroll
    for (int i = 0; i < 4; i++)
#pragma unroll
      for (int j = 0; j < 4; j++)
        acc[i][j] = MFMA16(af[i], bfr[j], acc[i][j], 0, 0, 0);

    if (ti + 1 < nt) __syncthreads();
  }

  if (OUT32) {
    float* ep = (float*)smem;
    float* co = (float*)Cv + (long)b * sC;
    const int band = wm >> 2;
    const int tr = t >> 3;
    const int tcb = (t & 7) * 16;
    const int growb = tm + (tr >> 4) * 64 + (tr & 15);
#pragma unroll
    for (int i = 0; i < 4; i++) {
      __syncthreads();
#pragma unroll
      for (int j = 0; j < 4; j++) {
        const int colb = wn + j * 16 + mr;
#pragma unroll
        for (int r = 0; r < 4; r++) {
          const int lr = band + q * 4 + r;
          ep[lr * 128 + ((colb + lr * 4) & 127)] = acc[i][j][r];
        }
      }
      __syncthreads();
      const int gr = growb + i * 16;
      const long rbase = (long)gr * ldc;
      const float* eprow = ep + tr * 128;
      const int rot = tr * 4;
#pragma unroll
      for (int k = 0; k < 4; k++) {
        const int lc = tcb + k * 4;
        f32x4 x = *(const f32x4*)&eprow[(lc + rot) & 127];
        x *= scale;
        *(f32x4*)&co[rbase + tn + lc] = x;
      }
    }
  } else {
#pragma unroll
    for (int i = 0; i < 4; i++) {
#pragma unroll
      for (int j = 0; j < 4; j++) {
        const int row0 = tm + wm + i * 16 + q * 4;
        const int col  = tn + wn + j * 16 + mr;
        const f32x4 v = acc[i][j];
#pragma unroll
        for (int r = 0; r < 4; r++) {
          float x = v[r] * scale;
          ((unsigned short*)Cv + (long)b * sC)[(long)(row0 + r) * ldc + col] = f2bf(x);
        }
      }
    }
  }
}

// one block per row of 2048 fp32 logits (mask pre-applied as NEGINF upstream):
// max -> sumexp -> normalize in place; optional bf16 copy to Pb.
__global__ __launch_bounds__(256) void softmax_rows_f32(
    float* __restrict__ P, unsigned short* __restrict__ Pb)
{
  const size_t row = blockIdx.x;
  float* p = P + row * 2048;
  const int t = threadIdx.x, lane = t & 63, wv = t >> 6;
  f32x4 a = *(const f32x4*)(p + t * 8);
  f32x4 c = *(const f32x4*)(p + t * 8 + 4);
  float x[8] = {a[0], a[1], a[2], a[3], c[0], c[1], c[2], c[3]};
  float mx = x[0];
#pragma unroll
  for (int j = 1; j < 8; j++) mx = fmaxf(mx, x[j]);
#pragma unroll
  for (int o = 32; o > 0; o >>= 1) mx = fmaxf(mx, __shfl_xor(mx, o));
  __shared__ float rm[4], rs[4];
  if (lane == 0) rm[wv] = mx;
  __syncthreads();
  mx = fmaxf(fmaxf(rm[0], rm[1]), fmaxf(rm[2], rm[3]));
  float e[8], s = 0.f;
#pragma unroll
  for (int j = 0; j < 8; j++) { e[j] = __expf(x[j] - mx); s += e[j]; }
#pragma unroll
  for (int o = 32; o > 0; o >>= 1) s += __shfl_xor(s, o);
  if (lane == 0) rs[wv] = s;
  __syncthreads();
  s = rs[0] + rs[1] + rs[2] + rs[3];
  // fully-masked row: mx stays NEGINF -> reference (softmax * mask) = 0
  const float linv = (mx < -1.0e5f) ? 0.f : 1.f / s;
  f32x4 o0 = {e[0] * linv, e[1] * linv, e[2] * linv, e[3] * linv};
  f32x4 o1 = {e[4] * linv, e[5] * linv, e[6] * linv, e[7] * linv};
  *(f32x4*)(p + t * 8) = o0;
  *(f32x4*)(p + t * 8 + 4) = o1;
  if (Pb) {
    ushort8v ob;
    ob[0] = f2bf(o0[0]); ob[1] = f2bf(o0[1]); ob[2] = f2bf(o0[2]); ob[3] = f2bf(o0[3]);
    ob[4] = f2bf(o1[0]); ob[5] = f2bf(o1[1]); ob[6] = f2bf(o1[2]); ob[7] = f2bf(o1[3]);
    *(ushort8v*)(Pb + row * 2048 + t * 8) = ob;
  }
}

// per-batch transpose+convert (fallback path only)
__global__ __launch_bounds__(256) void cvt_t_v(
    const float* __restrict__ src, unsigned short* __restrict__ dst)
{
  const int b = blockIdx.z;
  __shared__ float tile[32][33];
  const int s0 = blockIdx.x * 32, i0 = blockIdx.y * 32;
  const int tx = threadIdx.x & 31, ty = threadIdx.x >> 5;
#pragma unroll
  for (int r = 0; r < 4; r++) {
    const int srow = ty + r * 8;
    tile[srow][tx] = src[((size_t)b * 2048 + s0 + srow) * 512 + i0 + tx];
  }
  __syncthreads();
#pragma unroll
  for (int r = 0; r < 4; r++) {
    const int irow = ty + r * 8;
    dst[((size_t)b * 512 + i0 + irow) * 2048 + s0 + tx] = f2bf(tile[tx][irow]);
  }
}

// prep: fused cvt3 (blocks 0..4095) + transpose_w (blocks 4096..4351)
__global__ __launch_bounds__(256) void prep(
    const float* __restrict__ Xq, const float* __restrict__ Xk,
    const float* __restrict__ Xv,
    unsigned short* __restrict__ dq, unsigned short* __restrict__ dk,
    unsigned short* __restrict__ dv,
    const float* __restrict__ W0, const float* __restrict__ W1,
    const float* __restrict__ W2,
    unsigned short* __restrict__ T0, unsigned short* __restrict__ T1,
    unsigned short* __restrict__ T2)
{
  const int y = blockIdx.y;
  if (blockIdx.x < 4096) {
    const float* s = y == 0 ? Xq : (y == 1 ? Xk : Xv);
    unsigned short* d = y == 0 ? dq : (y == 1 ? dk : dv);
    const size_t i = ((size_t)blockIdx.x * 256 + threadIdx.x) * 8;
    const float4 a = *(const float4*)(s + i);
    const float4 b = *(const float4*)(s + i + 4);
    ushort8v o;
    o[0] = f2bf(a.x); o[1] = f2bf(a.y); o[2] = f2bf(a.z); o[3] = f2bf(a.w);
    o[4] = f2bf(b.x); o[5] = f2bf(b.y); o[6] = f2bf(b.z); o[7] = f2bf(b.w);
    *(ushort8v*)(d + i) = o;
  } else {
    const float* W = y == 0 ? W0 : (y == 1 ? W1 : W2);
    unsigned short* T = y == 0 ? T0 : (y == 1 ? T1 : T2);
    __shared__ float tile[32][33];
    const int id = blockIdx.x - 4096;            // 0..255 -> 16x16 tiles
    const int bx = (id & 15) * 32, by = (id >> 4) * 32;
    const int tx = threadIdx.x & 31, ty = threadIdx.x >> 5;
#pragma unroll
    for (int i = 0; i < 4; i++) {
      const int r = ty + i * 8;
      tile[r][tx] = W[(size_t)(by + r) * 512 + bx + tx];
    }
    __syncthreads();
#pragma unroll
    for (int i = 0; i < 4; i++) {
      const int r = ty + i * 8;
      T[(size_t)(bx + r) * 512 + by + tx] = f2bf(tile[tx][r]);
    }
  }
}

extern "C" void kernel_launch(void* const* d_in, const int* in_sizes, int n_in,
                              void* d_out, int out_size, void* d_ws, size_t ws_size,
                              hipStream_t stream) {
  const float* Xq = (const float*)d_in[0];
  const float* Xk = (const float*)d_in[1];
  const float* Xv = (const float*)d_in[2];
  const int*   mk = (const int*)d_in[3];
  const float* Wq = (const float*)d_in[4];
  const float* Wk = (const float*)d_in[5];
  const float* Wv = (const float*)d_in[6];

  float* z = (float*)d_out;                          // [8,2048,512] fp32
  float* P = z + (size_t)8 * 2048 * 512;             // [8,2048,2048] fp32

  // ws layout (bf16 shorts): Wtq|Wtk|Wtv (3x262144), buf1 (8388608),
  // buf2 (8388608), Pb (33554432) -> 102236160 bytes total.
  unsigned short* w    = (unsigned short*)d_ws;
  unsigned short* Wtq  = w;
  unsigned short* Wtv  = w + 524288;
  unsigned short* buf1 = w + 786432;                 // Qs; later Vwt / Xvt
  unsigned short* buf2 = buf1 + 8388608;             // Ks; later T1 (fallback)
  unsigned short* Pb   = buf2 + 8388608;
  const bool use_pb = ws_size >= (size_t)102236160;

  // bf16 scratch overlays in d_out regions written later:
  unsigned short* Xqkb = (unsigned short*)P;         // [2][8388608] (Xq,Xk)
  unsigned short* Xvb  = (unsigned short*)z;         // [8388608]   (Xv)

  const float inv_scale = 0.21022410381342863f;      // 512^-0.25

  // 1) prep: bf16 conversions + weight transposes
  prep<<<dim3(4352, 3), 256, 0, stream>>>(
      Xq, Xk, Xv, Xqkb, Xqkb + 8388608, Xvb,
      Wq, Wk, Wv, Wtq, Wtq + 262144, Wtv);

  // 2) Q and K projections in one launch
  proj3<<<dim3(128, 4, 2), 256, 0, stream>>>(
      Xqkb, Wtq, buf1, Wtv, Xvb, buf1, inv_scale, 0);

  // 3) scores: Qs @ Ks^T + mask -> P (fp32 logits, masked NEGINF)
  gemm_sc<<<dim3(16, 16, 8), 256, 0, stream>>>(buf1, buf2, P, mk);

  // 4) softmax: P -> attn_p (in place) [+ Pb bf16]
  softmax_rows_f32<<<dim3(16384), 256, 0, stream>>>(P, use_pb ? Pb : nullptr);

  if (use_pb) {
    // 5) Vw^T[b][e][s] into buf1 (Qs dead after scores)
    proj3<<<dim3(32, 16, 1), 256, 0, stream>>>(
        Xqkb, Wtq, buf1, Wtv, Xvb, buf1, inv_scale, 2);
    // 6) z = Pb @ Vwt^T (fp32 out)
    gemm_z<<<dim3(16, 4, 8), 256, 0, stream>>>(Pb, buf1, z);
  } else {
    // fallback: A32 PV (reads fp32 attn_p) + z GEMM
    cvt_t_v<<<dim3(64, 16, 8), 256, 0, stream>>>(Xv, buf1);
    gemm_nt<true, false><<<dim3(16, 4, 8), 256, 0, stream>>>(
        P, buf1, buf2, 2048, 2048, 2048, 512,
        4194304, 1048576, 1048576, 1.0f);
    gemm_nt<false, true><<<dim3(128, 4, 1), 256, 0, stream>>>(
        buf2, Wtv, z, 512, 512, 512, 512, 0, 0, 0, 1.0f);
  }
}